// Round 1
// baseline (455.626 us; speedup 1.0000x reference)
//
#include <hip/hip_runtime.h>

// MakeCutouts: 32 cutouts of (8,3,512,512) fp32, each adaptive-avg-pooled to
// 224x224. Output (32*8, 3, 224, 224) fp32.
//
// Write-BW-bound: 154 MB out writes vs 25 MB in (cache-resident).
// Each thread computes 4 consecutive output pixels -> float4 store.

constexpr int OUTSZ = 224;
constexpr int BB    = 8;
constexpr int CC    = 3;
constexpr int HH    = 512;
constexpr int WW    = 512;
constexpr int CUTN  = 32;

// total output elems = 32*8*3*224*224 = 38,535,168 ; /4 per thread
constexpr int TOTAL_V4 = CUTN * BB * CC * OUTSZ * (OUTSZ / 4);  // 9,633,792

__global__ __launch_bounds__(256) void make_cutouts_kernel(
    const float* __restrict__ x,
    const int*   __restrict__ sizes,
    const int*   __restrict__ offy,
    const int*   __restrict__ offx,
    float*       __restrict__ out)
{
    int idx = blockIdx.x * 256 + threadIdx.x;
    if (idx >= TOTAL_V4) return;

    // Decompose: idx -> (cutout i, batch b, chan c, row p, qvec)
    int qv = idx % (OUTSZ / 4);
    int t  = idx / (OUTSZ / 4);
    int p  = t % OUTSZ;  t /= OUTSZ;
    int c  = t % CC;     t /= CC;
    int b  = t % BB;
    int i  = t / BB;

    // Wave-uniform per-cutout params (whole wave has same i except at plane
    // boundaries) -> broadcast loads.
    int S  = sizes[i];
    int y0 = offy[i];
    int x0 = offx[i];

    const float* base = x + (((size_t)(b * CC + c) * HH + y0) * WW + x0);

    // torch adaptive_avg_pool2d bin for output row p over source size S:
    //   [floor(p*S/OUT), ceil((p+1)*S/OUT))
    int sp = (p * S) / OUTSZ;
    int ep = ((p + 1) * S + OUTSZ - 1) / OUTSZ;
    int nrows = ep - sp;

    float res[4];
#pragma unroll
    for (int k = 0; k < 4; ++k) {
        int q  = qv * 4 + k;
        int sq = (q * S) / OUTSZ;
        int eq = ((q + 1) * S + OUTSZ - 1) / OUTSZ;
        float sum = 0.0f;
        for (int r = sp; r < ep; ++r) {
            const float* row = base + (size_t)r * WW;
            for (int col = sq; col < eq; ++col) {
                sum += row[col];
            }
        }
        res[k] = sum / (float)(nrows * (eq - sq));
    }

    float4 o = make_float4(res[0], res[1], res[2], res[3]);
    reinterpret_cast<float4*>(out)[idx] = o;
}

extern "C" void kernel_launch(void* const* d_in, const int* in_sizes, int n_in,
                              void* d_out, int out_size, void* d_ws, size_t ws_size,
                              hipStream_t stream) {
    const float* x     = (const float*)d_in[0];
    const int*   sizes = (const int*)d_in[1];
    const int*   offy  = (const int*)d_in[2];
    const int*   offx  = (const int*)d_in[3];
    // d_in[4] = cut_size (==224), compile-time constant here.
    float* out = (float*)d_out;

    const int block = 256;
    const int grid  = (TOTAL_V4 + block - 1) / block;
    make_cutouts_kernel<<<grid, block, 0, stream>>>(x, sizes, offy, offx, out);
}

// Round 2
// 438.356 us; speedup vs baseline: 1.0394x; 1.0394x over previous
//
#include <hip/hip_runtime.h>

// MakeCutouts: 32 cutouts of (8,3,512,512) fp32, each adaptive-avg-pooled to
// 224x224. Output (32*8, 3, 224, 224) fp32.
//
// R1 showed: latency/transaction-bound. Scattered 4B gathers (lane stride
// ~26B) waste ~24/27 of every 64B line. R2: stage input bands in LDS with
// dense coalesced loads; compute bins from LDS.

constexpr int OUTSZ  = 224;
constexpr int BB     = 8;
constexpr int CC     = 3;
constexpr int HH     = 512;
constexpr int WW     = 512;
constexpr int CUTN   = 32;

constexpr int TILE_P  = 8;              // output rows per block
constexpr int NBANDS  = OUTSZ / TILE_P; // 28
// max input rows per band: ceil(8*512/224) + 1 = 20
constexpr int MAXROWS = 20;

constexpr int NBLOCKS = CUTN * BB * CC * NBANDS; // 21504

__global__ __launch_bounds__(256) void make_cutouts_kernel(
    const float* __restrict__ x,
    const int*   __restrict__ sizes,
    const int*   __restrict__ offy,
    const int*   __restrict__ offx,
    float*       __restrict__ out)
{
    __shared__ float tile[MAXROWS * WW];  // 40 KB

    int gid  = blockIdx.x;
    int band = gid % NBANDS;  int t = gid / NBANDS;
    int c    = t % CC;        t /= CC;
    int b    = t % BB;
    int i    = t / BB;

    // wave-uniform per-cutout params -> scalar broadcast
    int S  = sizes[i];
    int y0 = offy[i];
    int x0 = offx[i];

    int p0 = band * TILE_P;
    // input row range for this band of output rows (torch adaptive bins):
    int r0 = (p0 * S) / OUTSZ;                                // floor
    int r1 = ((p0 + TILE_P) * S + OUTSZ - 1) / OUTSZ;         // ceil
    int nr = r1 - r0;                                         // <= 20

    const float* src = x + (((size_t)(b * CC + c) * HH + (y0 + r0)) * WW + x0);

    // Dense coalesced staging: nr rows x S cols. Lane i reads element i of
    // each row chunk -> every byte of every 64B line is used.
    for (int r = 0; r < nr; ++r) {
        const float* row = src + (size_t)r * WW;
        float*       dst = tile + r * WW;
        for (int col = threadIdx.x; col < S; col += 256)
            dst[col] = row[col];
    }
    __syncthreads();

    // Each thread computes 7 of the 8*224 = 1792 tile pixels; consecutive
    // tids -> consecutive output addresses (coalesced dword stores).
    float* outp = out + ((size_t)((i * BB + b) * CC + c) * OUTSZ + p0) * OUTSZ;
    for (int j = threadIdx.x; j < TILE_P * OUTSZ; j += 256) {
        int lp = j / OUTSZ;          // compile-time divisor -> magic mul
        int q  = j - lp * OUTSZ;
        int p  = p0 + lp;

        int sp = (p * S) / OUTSZ - r0;
        int ep = ((p + 1) * S + OUTSZ - 1) / OUTSZ - r0;
        int sq = (q * S) / OUTSZ;
        int eq = ((q + 1) * S + OUTSZ - 1) / OUTSZ;

        float sum = 0.0f;
        for (int r = sp; r < ep; ++r) {
            const float* trow = tile + r * WW;
            for (int col = sq; col < eq; ++col)
                sum += trow[col];
        }
        outp[j] = sum / (float)((ep - sp) * (eq - sq));
    }
}

extern "C" void kernel_launch(void* const* d_in, const int* in_sizes, int n_in,
                              void* d_out, int out_size, void* d_ws, size_t ws_size,
                              hipStream_t stream) {
    const float* x     = (const float*)d_in[0];
    const int*   sizes = (const int*)d_in[1];
    const int*   offy  = (const int*)d_in[2];
    const int*   offx  = (const int*)d_in[3];
    float* out = (float*)d_out;

    make_cutouts_kernel<<<NBLOCKS, 256, 0, stream>>>(x, sizes, offy, offx, out);
}

// Round 4
// 256.152 us; speedup vs baseline: 1.7787x; 1.7113x over previous
//
#include <hip/hip_runtime.h>

// MakeCutouts: 32 cutouts of (8,3,512,512) fp32 -> adaptive avg pool 224x224.
//
// R3 bug: bins can be 4 wide when S > 448 (S/224 > 2). Fix: 4x4 unrolled
// window with cndmask-masked sums; block-uniform 3x3 fast path when S <= 448.
// Staging: full 512-wide rows -> band is ONE contiguous region -> flat float4
// copy (coalesced 16B/lane, ds_write_b128). TILE_P=4 keeps tile at 22.5 KB
// (7 blocks/CU).

constexpr int OUTSZ = 224;
constexpr int BB    = 8;
constexpr int CC    = 3;
constexpr int HH    = 512;
constexpr int WW    = 512;
constexpr int CUTN  = 32;

constexpr int TILE_P  = 4;
constexpr int NBANDS  = OUTSZ / TILE_P;  // 56
// staged rows nr <= ceil(4*512/224)+1 = 11 (rows 0..10); window reads reach
// row sp+3 <= ceil(3*512/224)+3 = 10 and col x0+sq+3 <= 514.
constexpr int LDSF    = 10 * WW + 516;   // 5636 floats = 22544 B
constexpr int NBLOCKS = CUTN * BB * CC * NBANDS;  // 43008

template <int WIN>
__device__ __forceinline__ void pool_pixels(const float* __restrict__ tile,
                                            float* __restrict__ outp,
                                            int S, int x0, int r0, int p0)
{
    for (int j = threadIdx.x; j < TILE_P * OUTSZ; j += 256) {
        int lp = j / OUTSZ;                 // const divisor -> magic mul
        int q  = j - lp * OUTSZ;
        int p  = p0 + lp;

        int sp = (p * S) / OUTSZ - r0;                        // 0..7
        int wp = ((p + 1) * S + OUTSZ - 1) / OUTSZ - r0 - sp; // 1..WIN
        int sq = (q * S) / OUTSZ;
        int wq = ((q + 1) * S + OUTSZ - 1) / OUTSZ - sq;      // 1..WIN

        const float* t0 = tile + sp * WW + x0 + sq;
        float z = 0.0f;
        float rowsum[WIN];
#pragma unroll
        for (int r = 0; r < WIN; ++r) {
            const float* tr = t0 + r * WW;
            // adjacent cols -> compiler merges to ds_read2_b32; masked-off
            // lanes select z (no garbage/NaN propagation).
            float s = tr[0];
#pragma unroll
            for (int k = 1; k < WIN; ++k)
                s += (wq > k) ? tr[k] : z;
            rowsum[r] = s;
        }
        float sum = rowsum[0];
#pragma unroll
        for (int r = 1; r < WIN; ++r)
            sum += (wp > r) ? rowsum[r] : z;

        float invp = (wp == 1) ? 1.0f : (wp == 2) ? 0.5f
                   : (wp == 3) ? (1.0f / 3.0f) : 0.25f;
        float invq = (wq == 1) ? 1.0f : (wq == 2) ? 0.5f
                   : (wq == 3) ? (1.0f / 3.0f) : 0.25f;
        outp[j] = sum * invp * invq;
    }
}

__global__ __launch_bounds__(256) void make_cutouts_kernel(
    const float* __restrict__ x,
    const int*   __restrict__ sizes,
    const int*   __restrict__ offy,
    const int*   __restrict__ offx,
    float*       __restrict__ out)
{
    __shared__ float tile[LDSF];

    int gid  = blockIdx.x;
    int band = gid % NBANDS;  int t = gid / NBANDS;
    int c    = t % CC;        t /= CC;
    int b    = t % BB;
    int i    = t / BB;

    // block-uniform per-cutout params -> scalar broadcast
    int S  = sizes[i];
    int y0 = offy[i];
    int x0 = offx[i];

    int p0 = band * TILE_P;
    int r0 = (p0 * S) / OUTSZ;
    int r1 = ((p0 + TILE_P) * S + OUTSZ - 1) / OUTSZ;
    int nr = r1 - r0;                       // <= 11

    // Full-width rows: band = ONE contiguous nr*512-float region, 16B aligned.
    const float4* src4  = (const float4*)(x + (size_t)((b * CC + c) * HH + y0 + r0) * WW);
    float4*       tile4 = (float4*)tile;
    int n4 = nr * (WW / 4);
    for (int v = threadIdx.x; v < n4; v += 256)
        tile4[v] = src4[v];
    __syncthreads();

    float* outp = out + ((size_t)((i * BB + b) * CC + c) * OUTSZ + p0) * OUTSZ;

    if (S <= 2 * OUTSZ)  // block-uniform branch: max bin width 3
        pool_pixels<3>(tile, outp, S, x0, r0, p0);
    else                 // S in (448,512]: max bin width 4
        pool_pixels<4>(tile, outp, S, x0, r0, p0);
}

extern "C" void kernel_launch(void* const* d_in, const int* in_sizes, int n_in,
                              void* d_out, int out_size, void* d_ws, size_t ws_size,
                              hipStream_t stream) {
    const float* x     = (const float*)d_in[0];
    const int*   sizes = (const int*)d_in[1];
    const int*   offy  = (const int*)d_in[2];
    const int*   offx  = (const int*)d_in[3];
    float* out = (float*)d_out;

    make_cutouts_kernel<<<NBLOCKS, 256, 0, stream>>>(x, sizes, offy, offx, out);
}